// Round 6
// baseline (418.444 us; speedup 1.0000x reference)
//
#include <hip/hip_runtime.h>

// Problem constants
#define B_TOT 65536
#define WS_P1W 4096                 // permuted bf16 p1W: 48*512*2 = 49152 B
#define WS_EV  (1u << 20)           // per-batch blocks: 512B E + 1024B V = 1536 B * 65536
#define EV_BYTES 100663296u         // 65536 * 1536
#define WS_PART (WS_EV + EV_BYTES)  // per-block D partials: 16384 * 256 * 4 = 16 MB

typedef float f32x4 __attribute__((ext_vector_type(4)));
typedef short s16x8 __attribute__((ext_vector_type(8)));

__device__ __forceinline__ float bf2f(unsigned short h) {
    unsigned u = ((unsigned)h) << 16;
    return __builtin_bit_cast(float, u);
}
// cheap bf16 pair pack: round-half-up (add 0x8000) + v_perm_b32 high-half merge.
__device__ __forceinline__ unsigned pack2(float a, float b) {
    unsigned ua = __builtin_bit_cast(unsigned, a) + 0x8000u;
    unsigned ub = __builtin_bit_cast(unsigned, b) + 0x8000u;
    return __builtin_amdgcn_perm(ub, ua, 0x07060302u);  // lo16=a, hi16=b
}
__device__ __forceinline__ unsigned short f2bf(float f) {
    return (unsigned short)((__builtin_bit_cast(unsigned, f) + 0x8000u) >> 16);
}
__device__ __forceinline__ s16x8 cvt8(float4 a, float4 b) {
    uint4 u;
    u.x = pack2(a.x, a.y); u.y = pack2(a.z, a.w);
    u.z = pack2(b.x, b.y); u.w = pack2(b.z, b.w);
    return __builtin_bit_cast(s16x8, u);
}
#define MFMA(a, b, c) __builtin_amdgcn_mfma_f32_16x16x32_bf16((a), (b), (c), 0, 0, 0)

// ---------------------------------------------------------------------------
// k1: ONE BATCH PER WAVE (16384 blocks, 65536 waves — was 8 batches/wave on
// 8192 waves).  R0-R5 established: k1 is invariant (~120us) to VALU count,
// occupancy %, depth-1 prefetch, and partial 2-batch ILP — every per-wave
// knob nulled.  Remaining hypothesis: per-batch serial chain latency (LDS
// round-trip -> shuffles -> rsqrt -> exp) x 8 sequential chains per wave.
// 8x more waves = 8x fewer serial chains each; hardware TLP covers the rest.
// Weights re-read by 16384 blocks stay L2-resident (no HBM delta expected).
// Deferred normalization (R3), scalar post-add biases, plain coalesced
// per-block D-partial store (no global atomics).
// ---------------------------------------------------------------------------
__global__ __launch_bounds__(256) void k1_stats(
    const float* __restrict__ e1, const float* __restrict__ e2,
    const float* __restrict__ qW, const float* __restrict__ qb,
    const float* __restrict__ kW, const float* __restrict__ kb,
    const float* __restrict__ vW, const float* __restrict__ vb,
    char* __restrict__ ws) {

    const int tid = threadIdx.x;
    const int lane = tid & 63;
    const int widx = tid >> 6;
    const int col = lane & 15;      // n-index (e_lo / d) in MFMA layouts
    const int quad = lane >> 4;

    // [wave][Q/K][16 rows x 40 shorts padded] = 10 KiB
    __shared__ __align__(16) unsigned short qk_lds[4][2][16 * 40];
    __shared__ float Dblk[256];
    if (blockIdx.x == 0) ((float*)ws)[tid] = 0.f;  // zero D accumulators
    Dblk[tid] = 0.f;
    __syncthreads();

    // Weight B-fragments: B_h[k=l][n=e_lo] = W[e_lo+16h][l], lane holds 8 consecutive l.
    s16x8 wq[2], wk[2], wv[2];
    float bq[2], bk[2], bv[2];      // scalar post-add biases (per-lane row = col+16h)
#pragma unroll
    for (int h = 0; h < 2; ++h) {
        int row = col + 16 * h;
        const float4* pq = (const float4*)(qW + row * 32 + quad * 8);
        const float4* pk = (const float4*)(kW + row * 32 + quad * 8);
        const float4* pv = (const float4*)(vW + row * 32 + quad * 8);
        wq[h] = cvt8(pq[0], pq[1]);
        wk[h] = cvt8(pk[0], pk[1]);
        wv[h] = cvt8(pv[0], pv[1]);
        bq[h] = qb[row]; bk[h] = kb[row]; bv[h] = vb[row];
    }

    char* evbase = ws + WS_EV;
    const f32x4 z = {0.f, 0.f, 0.f, 0.f};

    const int b = blockIdx.x * 4 + widx;         // one batch per wave
    // A-fragments of X1, X2: lane holds X[c=col][l = quad*8 .. +7]
    const float4* x1p = (const float4*)(e1 + (size_t)b * 512 + col * 32 + quad * 8);
    const float4* x2p = (const float4*)(e2 + (size_t)b * 512 + col * 32 + quad * 8);
    float4 a0 = x1p[0], a1 = x1p[1];
    float4 b0 = x2p[0], b1 = x2p[1];
    s16x8 fx1 = cvt8(a0, a1);
    s16x8 fx2 = cvt8(b0, b1);

    char* bbase = evbase + (size_t)b * 1536;
    {   // Q -> LDS (C/D layout: value (h,r) = M[row=quad*4+r][e=col+16h];
        // LDS rows store permuted e' = e_lo*2 + h, shared by Q,K)
        f32x4 qa = MFMA(fx1, wq[0], z), qc = MFMA(fx2, wq[0], z);
        f32x4 qd = MFMA(fx1, wq[1], z), qe = MFMA(fx2, wq[1], z);
        unsigned* dst = (unsigned*)qk_lds[widx][0];
#pragma unroll
        for (int r = 0; r < 4; ++r)
            dst[(quad * 4 + r) * 20 + col] =
                pack2((qa[r] + bq[0]) * (qc[r] + bq[0]),
                      (qd[r] + bq[1]) * (qe[r] + bq[1]));
    }
    {   // K -> LDS
        f32x4 ka = MFMA(fx1, wk[0], z), kc = MFMA(fx2, wk[0], z);
        f32x4 kd = MFMA(fx1, wk[1], z), ke = MFMA(fx2, wk[1], z);
        unsigned* dst = (unsigned*)qk_lds[widx][1];
#pragma unroll
        for (int r = 0; r < 4; ++r)
            dst[(quad * 4 + r) * 20 + col] =
                pack2((ka[r] + bk[0]) * (kc[r] + bk[0]),
                      (kd[r] + bk[1]) * (ke[r] + bk[1]));
    }
    {   // V -> global, blocked for k2 B-frags: block(h, e_lo=col, c-half quad>>1)
        f32x4 va = MFMA(fx1, wv[0], z), vc = MFMA(fx2, wv[0], z);
        f32x4 vd = MFMA(fx1, wv[1], z), ve = MFMA(fx2, wv[1], z);
        uint2 vst0, vst1;
        vst0.x = pack2((va[0] + bv[0]) * (vc[0] + bv[0]),
                       (va[1] + bv[0]) * (vc[1] + bv[0]));
        vst0.y = pack2((va[2] + bv[0]) * (vc[2] + bv[0]),
                       (va[3] + bv[0]) * (vc[3] + bv[0]));
        vst1.x = pack2((vd[0] + bv[1]) * (ve[0] + bv[1]),
                       (vd[1] + bv[1]) * (ve[1] + bv[1]));
        vst1.y = pack2((vd[2] + bv[1]) * (ve[2] + bv[1]),
                       (vd[3] + bv[1]) * (ve[3] + bv[1]));
        *(uint2*)(bbase + 512 + ((0 * 16 + col) * 2 + (quad >> 1)) * 16 + (quad & 1) * 8) = vst0;
        *(uint2*)(bbase + 512 + ((1 * 16 + col) * 2 + (quad >> 1)) * 16 + (quad & 1) * 8) = vst1;
    }

    // ---- read back raw Q/K, S-MFMA + deferred norms + exp ----
    const unsigned short* qbuf = qk_lds[widx][0];
    const unsigned short* kbuf = qk_lds[widx][1];
    s16x8 aq  = *(const s16x8*)(qbuf + col * 40 + quad * 8);
    s16x8 bk8 = *(const s16x8*)(kbuf + col * 40 + quad * 8);
    f32x4 S = MFMA(aq, bk8, z);   // S_raw[c=quad*4+r][d=col]

    float ssq = 0.f, ssk = 0.f;
#pragma unroll
    for (int j = 0; j < 8; ++j) {
        float qf = bf2f((unsigned short)aq[j]);  ssq += qf * qf;
        float kf = bf2f((unsigned short)bk8[j]); ssk += kf * kf;
    }
    ssq += __shfl_xor(ssq, 16); ssq += __shfl_xor(ssq, 32);
    ssk += __shfl_xor(ssk, 16); ssk += __shfl_xor(ssk, 32);
    float invq = 1.f / fmaxf(sqrtf(ssq), 1e-12f);   // at lane: row c = col
    float invk = 1.f / fmaxf(sqrtf(ssk), 1e-12f);   // at lane: row d = col
    float iq0 = __shfl(invq, quad * 4 + 0);
    float iq1 = __shfl(invq, quad * 4 + 1);
    float iq2 = __shfl(invq, quad * 4 + 2);
    float iq3 = __shfl(invq, quad * 4 + 3);

    float ex0 = __expf(S[0] * (iq0 * invk));
    float ex1 = __expf(S[1] * (iq1 * invk));
    float ex2 = __expf(S[2] * (iq2 * invk));
    float ex3 = __expf(S[3] * (iq3 * invk));
    uint2 est; est.x = pack2(ex0, ex1); est.y = pack2(ex2, ex3);
    *(uint2*)(bbase + col * 32 + quad * 8) = est;   // E [d][c] bf16

    // Denominator: regs -> block LDS (atomics, conflict-free) -> coalesced store
    atomicAdd(&Dblk[col * 16 + quad * 4 + 0], ex0);
    atomicAdd(&Dblk[col * 16 + quad * 4 + 1], ex1);
    atomicAdd(&Dblk[col * 16 + quad * 4 + 2], ex2);
    atomicAdd(&Dblk[col * 16 + quad * 4 + 3], ex3);
    __syncthreads();
    ((float*)(ws + WS_PART))[(size_t)blockIdx.x * 256 + tid] = Dblk[tid];
}

// ---------------------------------------------------------------------------
// k1b: 96 blocks.  All blocks: build bf16 p1W permuted into k2's i' order.
// Blocks 0..15 additionally reduce the 16384x256 partials COALESCED (block g
// streams rows g*1024..+1023, threads cover the 256 columns contiguously)
// and atomicAdd into D[256] at ws[0..1KB).  Reciprocal lives in k2.
// ---------------------------------------------------------------------------
__global__ __launch_bounds__(256) void k1b_prep(const float* __restrict__ p1W,
                                                char* __restrict__ ws) {
    const int t = threadIdx.x;
    const int g = blockIdx.x;
    const int idx = g * 256 + t;                 // 96*256 = 24576
    {
        int jj   = idx & 7;
        int lane = (idx >> 3) & 63;
        int ktnt = idx >> 9;
        int kt = ktnt & 15, nt = ktnt >> 4;
        int n_lo = lane & 15, q8 = lane >> 4;
        int j2  = nt * 16 + n_lo;                // output neuron [0,48)
        int ip  = kt * 32 + q8 * 8 + jj;         // i' in [0,512)
        int e_lo = ip >> 5, qq = (ip >> 3) & 3, hh = (ip >> 2) & 1, r = ip & 3;
        int orig = (qq * 4 + r) * 32 + (e_lo + 16 * hh);
        ((unsigned short*)(ws + WS_P1W))[idx] = f2bf(p1W[j2 * 512 + orig]);
    }
    if (g < 16) {
        const float* part = (const float*)(ws + WS_PART);
        float s = 0.f;
#pragma unroll 8
        for (int r = 0; r < 1024; ++r)
            s += part[(size_t)(g * 1024 + r) * 256 + t];   // coalesced 1KB rows
        atomicAdd(((float*)ws) + t, s);          // 16 blocks x 256 atomics
    }
}

// ---------------------------------------------------------------------------
// k2: cooperative 4-wave block over ONE 16-batch group.  Phase1 (prefetched
// E/V loads): each wave computes 4 of the 16 per-batch out[d][e] rows into a
// shared 16KB H (bf16, XOR-swizzled chunks).  Phase2 (prefetched weights):
// each wave takes 4 of the 16 k-tiles of MLP1 (MFMA), partial accs reduced
// through LDS (aliased over H).  Phase3: ALL FOUR waves.  dinv computed
// locally (1/D, 8 divides per thread — D finalized by k1b).  UNCHANGED this
// round (isolating the k1 wave-count variable).
// ---------------------------------------------------------------------------
__global__ __launch_bounds__(256) void k2_apply(
    const char* __restrict__ ws, const float* __restrict__ p1b,
    const float* __restrict__ p2W, const float* __restrict__ p2b,
    float* __restrict__ out) {

    const int tid = threadIdx.x;
    const int lane = tid & 63;
    const int widx = tid >> 6;
    const int col = lane & 15;
    const int quad = lane >> 4;
    const int qm = quad & 1;        // mirrored address for upper quads

    __shared__ __align__(16) unsigned short Hs[16 * 512];   // 16 KiB
    float* P = (float*)Hs;          // aliased partial-sum buffer (12 KiB <= 16 KiB)

    // Hoisted tail constants — issued first, latency hidden under phases 1-2
    float p1bias[3], p2w[3][3];
#pragma unroll
    for (int nt = 0; nt < 3; ++nt) {
        p1bias[nt] = p1b[col + 16 * nt];
#pragma unroll
        for (int t2 = 0; t2 < 3; ++t2) p2w[nt][t2] = p2W[t2 * 48 + col + 16 * nt];
    }
    const float pb0 = p2b[0], pb1 = p2b[1], pb2 = p2b[2];

    // 1/denominator from D (k1b atomic-finalized), vector-loaded
    const float* Dws = (const float*)ws;
    const float4 dva = *(const float4*)(Dws + col * 16 + qm * 8);
    const float4 dvb = *(const float4*)(Dws + col * 16 + qm * 8 + 4);
    float dinv[8] = {1.f / dva.x, 1.f / dva.y, 1.f / dva.z, 1.f / dva.w,
                     1.f / dvb.x, 1.f / dvb.y, 1.f / dvb.z, 1.f / dvb.w};

    const char* evbase = ws + WS_EV;
    const unsigned short* p1wp = (const unsigned short*)(ws + WS_P1W);
    const int g = blockIdx.x;
    const f32x4 z = {0.f, 0.f, 0.f, 0.f};
    const s16x8 zz = {0, 0, 0, 0, 0, 0, 0, 0};

    // Phase 1: out[d][e] for batches i = widx*4 .. +3 -> H rows (bf16, swizzled)
    {
        const char* bb0 = evbase + (size_t)(g * 16 + widx * 4) * 1536;
        const int eoff  = col * 32 + qm * 16;
        const int voff0 = 512 + (col * 2 + qm) * 16;
        const int voff1 = 512 + ((16 + col) * 2 + qm) * 16;
        s16x8 ne  = *(const s16x8*)(bb0 + eoff);
        s16x8 nv0 = *(const s16x8*)(bb0 + voff0);
        s16x8 nv1 = *(const s16x8*)(bb0 + voff1);
#pragma unroll
        for (int ii = 0; ii < 4; ++ii) {
            s16x8 eraw = ne, bf0 = nv0, bf1 = nv1;
            if (ii < 3) {
                const char* nb = bb0 + (size_t)(ii + 1) * 1536;
                ne  = *(const s16x8*)(nb + eoff);
                nv0 = *(const s16x8*)(nb + voff0);
                nv1 = *(const s16x8*)(nb + voff1);
            }
            float ef[8];
#pragma unroll
            for (int j = 0; j < 8; ++j)
                ef[j] = bf2f((unsigned short)eraw[j]) * dinv[j];
            uint4 ua;
            ua.x = pack2(ef[0], ef[1]); ua.y = pack2(ef[2], ef[3]);
            ua.z = pack2(ef[4], ef[5]); ua.w = pack2(ef[6], ef[7]);
            s16x8 afrag = __builtin_bit_cast(s16x8, ua);
            if (quad >= 2) { afrag = zz; bf0 = zz; bf1 = zz; }  // K-padding (c>=16 -> 0)
            f32x4 o0 = MFMA(afrag, bf0, z);   // out[d=quad*4+r][e=col]
            f32x4 o1 = MFMA(afrag, bf1, z);   // out[d=quad*4+r][e=col+16]
            uint4 uh;
            uh.x = pack2(o0[0], o0[1]); uh.y = pack2(o0[2], o0[3]);
            uh.z = pack2(o1[0], o1[1]); uh.w = pack2(o1[2], o1[3]);
            const int i = widx * 4 + ii;
            int chunk = (col * 4 + quad) ^ (i & 7);   // 16B-chunk XOR swizzle
            *(uint4*)(Hs + i * 512 + chunk * 8) = uh;
        }
    }
    __syncthreads();

    // Phase 2: MLP1 — H[16 x 512] @ p1Wp^T, wave widx handles kt = widx*4..+3
    f32x4 acc[3] = {z, z, z};
    {
        const int kt0 = widx * 4;
        s16x8 nw0 = *(const s16x8*)(p1wp + ((0 * 16 + kt0) * 64 + lane) * 8);
        s16x8 nw1 = *(const s16x8*)(p1wp + ((1 * 16 + kt0) * 64 + lane) * 8);
        s16x8 nw2 = *(const s16x8*)(p1wp + ((2 * 16 + kt0) * 64 + lane) * 8);
#pragma unroll
        for (int t2 = 0; t2 < 4; ++t2) {
            const int kt = widx * 4 + t2;
            s16x8 w0 = nw0, w1 = nw1, w2 = nw2;
            if (t2 < 3) {
                nw0 = *(const s16x8*)(p1wp + ((0 * 16 + kt + 1) * 64 + lane) * 8);
                nw1 = *(const s16x8*)(p1wp + ((1 * 16 + kt + 1) * 64 + lane) * 8);
                nw2 = *(const s16x8*)(p1wp + ((2 * 16 + kt + 1) * 64 + lane) * 8);
            }
            int chunk = (kt * 4 + quad) ^ (col & 7);
            s16x8 a = *(const s16x8*)(Hs + col * 512 + chunk * 8);
            acc[0] = MFMA(a, w0, acc[0]);
            acc[1] = MFMA(a, w1, acc[1]);
            acc[2] = MFMA(a, w2, acc[2]);
        }
    }
    __syncthreads();   // H reads done before P overwrites it

    // partials -> LDS: P[widx][lane][nt*4+r], lane stride 12 floats (48B)
#pragma unroll
    for (int nt = 0; nt < 3; ++nt)
        *(f32x4*)(P + (widx * 64 + lane) * 12 + nt * 4) = acc[nt];
    __syncthreads();

    // Phase 3: all 4 waves — wave widx handles r = widx (batches quad*4+widx)
    {
        float s3[3] = {0.f, 0.f, 0.f};
#pragma unroll
        for (int w = 0; w < 4; ++w)
#pragma unroll
            for (int nt = 0; nt < 3; ++nt)
                s3[nt] += P[(w * 64 + lane) * 12 + nt * 4 + widx];
        float pp[3] = {0.f, 0.f, 0.f};
#pragma unroll
        for (int nt = 0; nt < 3; ++nt) {
            float hv = fmaxf(s3[nt] + p1bias[nt], 0.f);
            pp[0] += hv * p2w[nt][0];
            pp[1] += hv * p2w[nt][1];
            pp[2] += hv * p2w[nt][2];
        }
#pragma unroll
        for (int m = 1; m <= 8; m <<= 1) {
            pp[0] += __shfl_xor(pp[0], m);
            pp[1] += __shfl_xor(pp[1], m);
            pp[2] += __shfl_xor(pp[2], m);
        }
        float h0 = pp[0] + pb0, h1 = pp[1] + pb1, h2 = pp[2] + pb2;
        float inv = 1.f / fmaxf(sqrtf(h0 * h0 + h1 * h1 + h2 * h2), 1e-12f);
        if (col < 3) {
            float v = (col == 0) ? h0 : ((col == 1) ? h1 : h2);
            out[(size_t)(g * 16 + quad * 4 + widx) * 3 + col] = v * inv;
        }
    }
}

// ---------------------------------------------------------------------------
extern "C" void kernel_launch(void* const* d_in, const int* in_sizes, int n_in,
                              void* d_out, int out_size, void* d_ws, size_t ws_size,
                              hipStream_t stream) {
    const float* e1  = (const float*)d_in[0];
    const float* e2  = (const float*)d_in[1];
    const float* qW  = (const float*)d_in[2];
    const float* qb  = (const float*)d_in[3];
    const float* kW  = (const float*)d_in[4];
    const float* kb  = (const float*)d_in[5];
    const float* vW  = (const float*)d_in[6];
    const float* vb  = (const float*)d_in[7];
    const float* p1W = (const float*)d_in[8];
    const float* p1b = (const float*)d_in[9];
    const float* p2W = (const float*)d_in[10];
    const float* p2b = (const float*)d_in[11];
    float* out = (float*)d_out;
    char* ws = (char*)d_ws;

    k1_stats<<<16384, 256, 0, stream>>>(e1, e2, qW, qb, kW, kb, vW, vb, ws);
    k1b_prep<<<96, 256, 0, stream>>>(p1W, ws);
    k2_apply<<<4096, 256, 0, stream>>>(ws, p1b, p2W, p2b, out);
}

// Round 8
// 353.966 us; speedup vs baseline: 1.1822x; 1.1822x over previous
//
#include <hip/hip_runtime.h>

// Problem constants
#define B_TOT 65536
#define WS_P1W 4096                 // permuted bf16 p1W: 48*512*2 = 49152 B
#define WS_EV  (1u << 20)           // per-batch blocks: 512B E + 1024B V = 1536 B * 65536

typedef float f32x4 __attribute__((ext_vector_type(4)));
typedef short s16x8 __attribute__((ext_vector_type(8)));
typedef unsigned u32x2 __attribute__((ext_vector_type(2)));   // nontemporal-compatible

__device__ __forceinline__ float bf2f(unsigned short h) {
    unsigned u = ((unsigned)h) << 16;
    return __builtin_bit_cast(float, u);
}
// cheap bf16 pair pack: round-half-up (add 0x8000) + v_perm_b32 high-half merge.
__device__ __forceinline__ unsigned pack2(float a, float b) {
    unsigned ua = __builtin_bit_cast(unsigned, a) + 0x8000u;
    unsigned ub = __builtin_bit_cast(unsigned, b) + 0x8000u;
    return __builtin_amdgcn_perm(ub, ua, 0x07060302u);  // lo16=a, hi16=b
}
__device__ __forceinline__ unsigned short f2bf(float f) {
    return (unsigned short)((__builtin_bit_cast(unsigned, f) + 0x8000u) >> 16);
}
__device__ __forceinline__ s16x8 cvt8(float4 a, float4 b) {
    uint4 u;
    u.x = pack2(a.x, a.y); u.y = pack2(a.z, a.w);
    u.z = pack2(b.x, b.y); u.w = pack2(b.z, b.w);
    return __builtin_bit_cast(s16x8, u);
}
#define MFMA(a, b, c) __builtin_amdgcn_mfma_f32_16x16x32_bf16((a), (b), (c), 0, 0, 0)

// ---------------------------------------------------------------------------
// k1: EXACT R3 structure (best measured: 122us, VGPR 52) — 8 batches/wave,
// 2048 blocks, bf16 MFMA linears w/ bias-in-accumulator, deferred
// normalization (S on raw Q/K, norms applied after), E=exp->ws, V->ws.
// R6 falsified wave-parallelism (8x waves, occ 51%, SLOWER); k1 is invariant
// to every per-wave/cross-wave knob tried — frozen at R3 shape.
// NEW vs R3: (a) blocks 0..95 also build the permuted bf16 p1W (k1b's
// permute folded in — consumed only by k2, stream-ordered safe);
// (b) D finalized by per-block global atomicAdd — partial buffer + reduce
// kernel DELETED (R5/R6: grid-starved reducer cost 30-60us); D zeroed by
// 1KB hipMemsetAsync; (c) E/V stores non-temporal via u32x2 ext-vector
// (one-shot data; keep inputs resident in L2/L3).
// ---------------------------------------------------------------------------
__global__ __launch_bounds__(256) void k1_stats(
    const float* __restrict__ e1, const float* __restrict__ e2,
    const float* __restrict__ qW, const float* __restrict__ qb,
    const float* __restrict__ kW, const float* __restrict__ kb,
    const float* __restrict__ vW, const float* __restrict__ vb,
    const float* __restrict__ p1W, char* __restrict__ ws) {

    const int tid = threadIdx.x;
    const int lane = tid & 63;
    const int widx = tid >> 6;
    const int col = lane & 15;      // n-index (e_lo / d) in MFMA layouts
    const int quad = lane >> 4;

    __shared__ __align__(16) unsigned short qk_lds[4][2][16 * 40]; // padded rows (80B)
    __shared__ float Dblk[256];
    Dblk[tid] = 0.f;

    // Folded k1b permute: blocks 0..95 each emit 256 elems of bf16 p1W in
    // k2's i' order.  Independent of batch work; read by k2 only.
    if (blockIdx.x < 96) {
        int idx = blockIdx.x * 256 + tid;        // 96*256 = 24576 = 48*512
        int jj   = idx & 7;
        int l2   = (idx >> 3) & 63;
        int ktnt = idx >> 9;
        int kt = ktnt & 15, nt = ktnt >> 4;
        int n_lo = l2 & 15, q8 = l2 >> 4;
        int j2  = nt * 16 + n_lo;                // output neuron [0,48)
        int ip  = kt * 32 + q8 * 8 + jj;         // i' in [0,512)
        int e_lo = ip >> 5, qq = (ip >> 3) & 3, hh = (ip >> 2) & 1, r = ip & 3;
        int orig = (qq * 4 + r) * 32 + (e_lo + 16 * hh);
        ((unsigned short*)(ws + WS_P1W))[idx] = f2bf(p1W[j2 * 512 + orig]);
    }
    __syncthreads();

    // Weight B-fragments: B_h[k=l][n=e_lo] = W[e_lo+16h][l], lane holds 8 consecutive l.
    s16x8 wq[2], wk[2], wv[2];
    f32x4 cbq[2], cbk[2], cbv[2];   // bias pre-loaded into MFMA accumulators
#pragma unroll
    for (int h = 0; h < 2; ++h) {
        int row = col + 16 * h;
        const float4* pq = (const float4*)(qW + row * 32 + quad * 8);
        const float4* pk = (const float4*)(kW + row * 32 + quad * 8);
        const float4* pv = (const float4*)(vW + row * 32 + quad * 8);
        wq[h] = cvt8(pq[0], pq[1]);
        wk[h] = cvt8(pk[0], pk[1]);
        wv[h] = cvt8(pv[0], pv[1]);
        float qv_ = qb[row], kv_ = kb[row], vv_ = vb[row];
        cbq[h] = (f32x4){qv_, qv_, qv_, qv_};
        cbk[h] = (f32x4){kv_, kv_, kv_, kv_};
        cbv[h] = (f32x4){vv_, vv_, vv_, vv_};
    }

    unsigned short* qbuf = qk_lds[widx][0];
    unsigned short* kbuf = qk_lds[widx][1];
    float dacc[4] = {0.f, 0.f, 0.f, 0.f};
    char* evbase = ws + WS_EV;
    const f32x4 z = {0.f, 0.f, 0.f, 0.f};

    const int gw = blockIdx.x * 4 + widx;
    for (int i = 0; i < 8; ++i) {
        const int b = gw * 8 + i;
        // A-fragments of X1, X2: lane holds X[c=col][l = quad*8 .. +7]
        const float4* x1p = (const float4*)(e1 + (size_t)b * 512 + col * 32 + quad * 8);
        const float4* x2p = (const float4*)(e2 + (size_t)b * 512 + col * 32 + quad * 8);
        float4 a0 = x1p[0], a1 = x1p[1];
        float4 b0 = x2p[0], b1 = x2p[1];
        s16x8 fx1 = cvt8(a0, a1);
        s16x8 fx2 = cvt8(b0, b1);

        // ---- Q: linears, product, LDS stage (transpose to A-frag layout) ----
        {
            f32x4 q1v[2], q2v[2];
#pragma unroll
            for (int h = 0; h < 2; ++h) {
                q1v[h] = MFMA(fx1, wq[h], cbq[h]);
                q2v[h] = MFMA(fx2, wq[h], cbq[h]);
            }
            // C/D layout: value (h,r) = M[row=quad*4+r][e=col+16h]; LDS rows
            // store permuted e' = e_lo*2 + h (perm shared by Q and K)
#pragma unroll
            for (int r = 0; r < 4; ++r) {
                int w = (quad * 4 + r) * 20 + col;   // uint index, row stride 20 words
                ((unsigned*)qbuf)[w] = pack2(q1v[0][r] * q2v[0][r],
                                             q1v[1][r] * q2v[1][r]);
            }
        }
        // ---- K: same ----
        {
            f32x4 k1v[2], k2v[2];
#pragma unroll
            for (int h = 0; h < 2; ++h) {
                k1v[h] = MFMA(fx1, wk[h], cbk[h]);
                k2v[h] = MFMA(fx2, wk[h], cbk[h]);
            }
#pragma unroll
            for (int r = 0; r < 4; ++r) {
                int w = (quad * 4 + r) * 20 + col;
                ((unsigned*)kbuf)[w] = pack2(k1v[0][r] * k2v[0][r],
                                             k1v[1][r] * k2v[1][r]);
            }
        }
        // ---- V: independent of the LDS round trip — fills its latency shadow
        char* bbase = evbase + (size_t)b * 1536;
        {
            f32x4 v1v[2], v2v[2];
#pragma unroll
            for (int h = 0; h < 2; ++h) {
                v1v[h] = MFMA(fx1, wv[h], cbv[h]);
                v2v[h] = MFMA(fx2, wv[h], cbv[h]);
            }
            // V stored blocked for k2 B-frags: block(h, e_lo=col, c-half quad>>1)
#pragma unroll
            for (int h = 0; h < 2; ++h) {
                u32x2 vst;
                vst.x = pack2(v1v[h][0] * v2v[h][0], v1v[h][1] * v2v[h][1]);
                vst.y = pack2(v1v[h][2] * v2v[h][2], v1v[h][3] * v2v[h][3]);
                __builtin_nontemporal_store(vst,
                    (u32x2*)(bbase + 512 + ((h * 16 + col) * 2 + (quad >> 1)) * 16 + (quad & 1) * 8));
            }
        }

        // ---- read back RAW Q as A-frag, K as B-frag; S-MFMA issues at once
        s16x8 aq  = *(const s16x8*)(qbuf + col * 40 + quad * 8);
        s16x8 bk8 = *(const s16x8*)(kbuf + col * 40 + quad * 8);
        f32x4 S = MFMA(aq, bk8, z);   // S_raw[c=quad*4+r][d=col]

        // ---- norms in parallel with the S-MFMA (deferred normalization)
        float ssq = 0.f, ssk = 0.f;
#pragma unroll
        for (int j = 0; j < 8; ++j) {
            float qf = bf2f((unsigned short)aq[j]);  ssq += qf * qf;
            float kf = bf2f((unsigned short)bk8[j]); ssk += kf * kf;
        }
        ssq += __shfl_xor(ssq, 16); ssq += __shfl_xor(ssq, 32);
        ssk += __shfl_xor(ssk, 16); ssk += __shfl_xor(ssk, 32);
        float invq = 1.f / fmaxf(sqrtf(ssq), 1e-12f);   // at lane: row c = col
        float invk = 1.f / fmaxf(sqrtf(ssk), 1e-12f);   // at lane: row d = col
        // transpose invq to row indexing (S rows are quad*4+r)
        float iq0 = __shfl(invq, quad * 4 + 0);
        float iq1 = __shfl(invq, quad * 4 + 1);
        float iq2 = __shfl(invq, quad * 4 + 2);
        float iq3 = __shfl(invq, quad * 4 + 3);

        float ex0 = __expf(S[0] * (iq0 * invk));
        float ex1 = __expf(S[1] * (iq1 * invk));
        float ex2 = __expf(S[2] * (iq2 * invk));
        float ex3 = __expf(S[3] * (iq3 * invk));
        dacc[0] += ex0; dacc[1] += ex1; dacc[2] += ex2; dacc[3] += ex3;
        // E stored [d][c] bf16: lane covers c = quad*4 .. +3 at row d=col
        u32x2 est; est.x = pack2(ex0, ex1); est.y = pack2(ex2, ex3);
        __builtin_nontemporal_store(est, (u32x2*)(bbase + col * 32 + quad * 8));
    }
    // Denominator: regs -> block LDS (conflict-free) -> 256 global atomics/block.
    // Blocks drain staggered over k1's span so same-address chains don't pile up.
#pragma unroll
    for (int r = 0; r < 4; ++r)
        atomicAdd(&Dblk[col * 16 + quad * 4 + r], dacc[r]);
    __syncthreads();
    atomicAdd(((float*)ws) + tid, Dblk[tid]);
}

// ---------------------------------------------------------------------------
// k2: cooperative 4-wave block over ONE 16-batch group (R3 structure, best
// measured).  Phase1 (prefetched E/V loads): each wave computes 4 of the 16
// per-batch out[d][e] rows into a shared 16KB H (bf16, XOR-swizzled chunks).
// Phase2 (prefetched weights): each wave takes 4 of the 16 k-tiles of MLP1
// (MFMA), partial accs reduced through LDS (aliased over H).  Phase3: all
// four waves.  dinv = 1/D computed locally (D finalized by k1's atomics).
// ---------------------------------------------------------------------------
__global__ __launch_bounds__(256) void k2_apply(
    const char* __restrict__ ws, const float* __restrict__ p1b,
    const float* __restrict__ p2W, const float* __restrict__ p2b,
    float* __restrict__ out) {

    const int tid = threadIdx.x;
    const int lane = tid & 63;
    const int widx = tid >> 6;
    const int col = lane & 15;
    const int quad = lane >> 4;
    const int qm = quad & 1;        // mirrored address for upper quads

    __shared__ __align__(16) unsigned short Hs[16 * 512];   // 16 KiB
    float* P = (float*)Hs;          // aliased partial-sum buffer (12 KiB <= 16 KiB)

    // Hoisted tail constants — issued first, latency hidden under phases 1-2
    float p1bias[3], p2w[3][3];
#pragma unroll
    for (int nt = 0; nt < 3; ++nt) {
        p1bias[nt] = p1b[col + 16 * nt];
#pragma unroll
        for (int t2 = 0; t2 < 3; ++t2) p2w[nt][t2] = p2W[t2 * 48 + col + 16 * nt];
    }
    const float pb0 = p2b[0], pb1 = p2b[1], pb2 = p2b[2];

    // 1/denominator from D (k1 atomic-finalized), vector-loaded
    const float* Dws = (const float*)ws;
    const float4 dva = *(const float4*)(Dws + col * 16 + qm * 8);
    const float4 dvb = *(const float4*)(Dws + col * 16 + qm * 8 + 4);
    float dinv[8] = {1.f / dva.x, 1.f / dva.y, 1.f / dva.z, 1.f / dva.w,
                     1.f / dvb.x, 1.f / dvb.y, 1.f / dvb.z, 1.f / dvb.w};

    const char* evbase = ws + WS_EV;
    const unsigned short* p1wp = (const unsigned short*)(ws + WS_P1W);
    const int g = blockIdx.x;
    const f32x4 z = {0.f, 0.f, 0.f, 0.f};
    const s16x8 zz = {0, 0, 0, 0, 0, 0, 0, 0};

    // Phase 1: out[d][e] for batches i = widx*4 .. +3 -> H rows (bf16, swizzled)
    {
        const char* bb0 = evbase + (size_t)(g * 16 + widx * 4) * 1536;
        const int eoff  = col * 32 + qm * 16;
        const int voff0 = 512 + (col * 2 + qm) * 16;
        const int voff1 = 512 + ((16 + col) * 2 + qm) * 16;
        s16x8 ne  = *(const s16x8*)(bb0 + eoff);
        s16x8 nv0 = *(const s16x8*)(bb0 + voff0);
        s16x8 nv1 = *(const s16x8*)(bb0 + voff1);
#pragma unroll
        for (int ii = 0; ii < 4; ++ii) {
            s16x8 eraw = ne, bf0 = nv0, bf1 = nv1;
            if (ii < 3) {
                const char* nb = bb0 + (size_t)(ii + 1) * 1536;
                ne  = *(const s16x8*)(nb + eoff);
                nv0 = *(const s16x8*)(nb + voff0);
                nv1 = *(const s16x8*)(nb + voff1);
            }
            float ef[8];
#pragma unroll
            for (int j = 0; j < 8; ++j)
                ef[j] = bf2f((unsigned short)eraw[j]) * dinv[j];
            uint4 ua;
            ua.x = pack2(ef[0], ef[1]); ua.y = pack2(ef[2], ef[3]);
            ua.z = pack2(ef[4], ef[5]); ua.w = pack2(ef[6], ef[7]);
            s16x8 afrag = __builtin_bit_cast(s16x8, ua);
            if (quad >= 2) { afrag = zz; bf0 = zz; bf1 = zz; }  // K-padding (c>=16 -> 0)
            f32x4 o0 = MFMA(afrag, bf0, z);   // out[d=quad*4+r][e=col]
            f32x4 o1 = MFMA(afrag, bf1, z);   // out[d=quad*4+r][e=col+16]
            uint4 uh;
            uh.x = pack2(o0[0], o0[1]); uh.y = pack2(o0[2], o0[3]);
            uh.z = pack2(o1[0], o1[1]); uh.w = pack2(o1[2], o1[3]);
            const int i = widx * 4 + ii;
            int chunk = (col * 4 + quad) ^ (i & 7);   // 16B-chunk XOR swizzle
            *(uint4*)(Hs + i * 512 + chunk * 8) = uh;
        }
    }
    __syncthreads();

    // Phase 2: MLP1 — H[16 x 512] @ p1Wp^T, wave widx handles kt = widx*4..+3
    f32x4 acc[3] = {z, z, z};
    {
        const int kt0 = widx * 4;
        s16x8 nw0 = *(const s16x8*)(p1wp + ((0 * 16 + kt0) * 64 + lane) * 8);
        s16x8 nw1 = *(const s16x8*)(p1wp + ((1 * 16 + kt0) * 64 + lane) * 8);
        s16x8 nw2 = *(const s16x8*)(p1wp + ((2 * 16 + kt0) * 64 + lane) * 8);
#pragma unroll
        for (int t2 = 0; t2 < 4; ++t2) {
            const int kt = widx * 4 + t2;
            s16x8 w0 = nw0, w1 = nw1, w2 = nw2;
            if (t2 < 3) {
                nw0 = *(const s16x8*)(p1wp + ((0 * 16 + kt + 1) * 64 + lane) * 8);
                nw1 = *(const s16x8*)(p1wp + ((1 * 16 + kt + 1) * 64 + lane) * 8);
                nw2 = *(const s16x8*)(p1wp + ((2 * 16 + kt + 1) * 64 + lane) * 8);
            }
            int chunk = (kt * 4 + quad) ^ (col & 7);
            s16x8 a = *(const s16x8*)(Hs + col * 512 + chunk * 8);
            acc[0] = MFMA(a, w0, acc[0]);
            acc[1] = MFMA(a, w1, acc[1]);
            acc[2] = MFMA(a, w2, acc[2]);
        }
    }
    __syncthreads();   // H reads done before P overwrites it

    // partials -> LDS: P[widx][lane][nt*4+r], lane stride 12 floats (48B)
#pragma unroll
    for (int nt = 0; nt < 3; ++nt)
        *(f32x4*)(P + (widx * 64 + lane) * 12 + nt * 4) = acc[nt];
    __syncthreads();

    // Phase 3: all 4 waves — wave widx handles r = widx (batches quad*4+widx)
    {
        float s3[3] = {0.f, 0.f, 0.f};
#pragma unroll
        for (int w = 0; w < 4; ++w)
#pragma unroll
            for (int nt = 0; nt < 3; ++nt)
                s3[nt] += P[(w * 64 + lane) * 12 + nt * 4 + widx];
        float pp[3] = {0.f, 0.f, 0.f};
#pragma unroll
        for (int nt = 0; nt < 3; ++nt) {
            float hv = fmaxf(s3[nt] + p1bias[nt], 0.f);
            pp[0] += hv * p2w[nt][0];
            pp[1] += hv * p2w[nt][1];
            pp[2] += hv * p2w[nt][2];
        }
#pragma unroll
        for (int m = 1; m <= 8; m <<= 1) {
            pp[0] += __shfl_xor(pp[0], m);
            pp[1] += __shfl_xor(pp[1], m);
            pp[2] += __shfl_xor(pp[2], m);
        }
        float h0 = pp[0] + pb0, h1 = pp[1] + pb1, h2 = pp[2] + pb2;
        float inv = 1.f / fmaxf(sqrtf(h0 * h0 + h1 * h1 + h2 * h2), 1e-12f);
        if (col < 3) {
            float v = (col == 0) ? h0 : ((col == 1) ? h1 : h2);
            out[(size_t)(g * 16 + quad * 4 + widx) * 3 + col] = v * inv;
        }
    }
}

// ---------------------------------------------------------------------------
extern "C" void kernel_launch(void* const* d_in, const int* in_sizes, int n_in,
                              void* d_out, int out_size, void* d_ws, size_t ws_size,
                              hipStream_t stream) {
    const float* e1  = (const float*)d_in[0];
    const float* e2  = (const float*)d_in[1];
    const float* qW  = (const float*)d_in[2];
    const float* qb  = (const float*)d_in[3];
    const float* kW  = (const float*)d_in[4];
    const float* kb  = (const float*)d_in[5];
    const float* vW  = (const float*)d_in[6];
    const float* vb  = (const float*)d_in[7];
    const float* p1W = (const float*)d_in[8];
    const float* p1b = (const float*)d_in[9];
    const float* p2W = (const float*)d_in[10];
    const float* p2b = (const float*)d_in[11];
    float* out = (float*)d_out;
    char* ws = (char*)d_ws;

    (void)hipMemsetAsync(ws, 0, 1024, stream);   // zero D accumulators (stream-ordered)
    k1_stats<<<2048, 256, 0, stream>>>(e1, e2, qW, qb, kW, kb, vW, vb, p1W, ws);
    k2_apply<<<4096, 256, 0, stream>>>(ws, p1b, p2W, p2b, out);
}

// Round 9
// 345.866 us; speedup vs baseline: 1.2098x; 1.0234x over previous
//
#include <hip/hip_runtime.h>

// Problem constants
#define B_TOT 65536
#define WS_P1W 4096                 // permuted bf16 p1W: 48*512*2 = 49152 B
#define WS_EV  (1u << 20)           // per-batch blocks: 512B E + 1024B V = 1536 B * 65536

typedef float f32x4 __attribute__((ext_vector_type(4)));
typedef short s16x8 __attribute__((ext_vector_type(8)));

__device__ __forceinline__ float bf2f(unsigned short h) {
    unsigned u = ((unsigned)h) << 16;
    return __builtin_bit_cast(float, u);
}
// cheap bf16 pair pack: round-half-up (add 0x8000) + v_perm_b32 high-half merge.
__device__ __forceinline__ unsigned pack2(float a, float b) {
    unsigned ua = __builtin_bit_cast(unsigned, a) + 0x8000u;
    unsigned ub = __builtin_bit_cast(unsigned, b) + 0x8000u;
    return __builtin_amdgcn_perm(ub, ua, 0x07060302u);  // lo16=a, hi16=b
}
__device__ __forceinline__ unsigned short f2bf(float f) {
    return (unsigned short)((__builtin_bit_cast(unsigned, f) + 0x8000u) >> 16);
}
__device__ __forceinline__ s16x8 cvt8(float4 a, float4 b) {
    uint4 u;
    u.x = pack2(a.x, a.y); u.y = pack2(a.z, a.w);
    u.z = pack2(b.x, b.y); u.w = pack2(b.z, b.w);
    return __builtin_bit_cast(s16x8, u);
}
#define MFMA(a, b, c) __builtin_amdgcn_mfma_f32_16x16x32_bf16((a), (b), (c), 0, 0, 0)

// ---------------------------------------------------------------------------
// k1: R3 structure (best measured: 122us, VGPR 52) — 8 batches/wave,
// 2048 blocks, bf16 MFMA linears w/ bias-in-accumulator, deferred
// normalization (S on raw Q/K, norms applied after), E=exp->ws, V->ws.
// R8 post-mortem: NON-TEMPORAL E/V stores were a mistake — E/V (96MB) is
// producer->consumer data that fits L3; nt bypassed the cache, slowing k1
// (~+13us) AND forcing k2 to re-read 96MB from HBM.  PLAIN stores restored.
// Kept from R8: (a) folded p1W permute (blocks 0..95); (b) D finalized by
// per-block global atomicAdd (R0-proven ~cheap), partial buffer + reduce
// kernel deleted (R5/R6: grid-starved reducer cost 30-60us); (c) 1KB
// hipMemsetAsync zeroes D.
// ---------------------------------------------------------------------------
__global__ __launch_bounds__(256) void k1_stats(
    const float* __restrict__ e1, const float* __restrict__ e2,
    const float* __restrict__ qW, const float* __restrict__ qb,
    const float* __restrict__ kW, const float* __restrict__ kb,
    const float* __restrict__ vW, const float* __restrict__ vb,
    const float* __restrict__ p1W, char* __restrict__ ws) {

    const int tid = threadIdx.x;
    const int lane = tid & 63;
    const int widx = tid >> 6;
    const int col = lane & 15;      // n-index (e_lo / d) in MFMA layouts
    const int quad = lane >> 4;

    __shared__ __align__(16) unsigned short qk_lds[4][2][16 * 40]; // padded rows (80B)
    __shared__ float Dblk[256];
    Dblk[tid] = 0.f;

    // Folded k1b permute: blocks 0..95 each emit 256 elems of bf16 p1W in
    // k2's i' order.  Independent of batch work; read by k2 only.
    if (blockIdx.x < 96) {
        int idx = blockIdx.x * 256 + tid;        // 96*256 = 24576 = 48*512
        int jj   = idx & 7;
        int l2   = (idx >> 3) & 63;
        int ktnt = idx >> 9;
        int kt = ktnt & 15, nt = ktnt >> 4;
        int n_lo = l2 & 15, q8 = l2 >> 4;
        int j2  = nt * 16 + n_lo;                // output neuron [0,48)
        int ip  = kt * 32 + q8 * 8 + jj;         // i' in [0,512)
        int e_lo = ip >> 5, qq = (ip >> 3) & 3, hh = (ip >> 2) & 1, r = ip & 3;
        int orig = (qq * 4 + r) * 32 + (e_lo + 16 * hh);
        ((unsigned short*)(ws + WS_P1W))[idx] = f2bf(p1W[j2 * 512 + orig]);
    }
    __syncthreads();

    // Weight B-fragments: B_h[k=l][n=e_lo] = W[e_lo+16h][l], lane holds 8 consecutive l.
    s16x8 wq[2], wk[2], wv[2];
    f32x4 cbq[2], cbk[2], cbv[2];   // bias pre-loaded into MFMA accumulators
#pragma unroll
    for (int h = 0; h < 2; ++h) {
        int row = col + 16 * h;
        const float4* pq = (const float4*)(qW + row * 32 + quad * 8);
        const float4* pk = (const float4*)(kW + row * 32 + quad * 8);
        const float4* pv = (const float4*)(vW + row * 32 + quad * 8);
        wq[h] = cvt8(pq[0], pq[1]);
        wk[h] = cvt8(pk[0], pk[1]);
        wv[h] = cvt8(pv[0], pv[1]);
        float qv_ = qb[row], kv_ = kb[row], vv_ = vb[row];
        cbq[h] = (f32x4){qv_, qv_, qv_, qv_};
        cbk[h] = (f32x4){kv_, kv_, kv_, kv_};
        cbv[h] = (f32x4){vv_, vv_, vv_, vv_};
    }

    unsigned short* qbuf = qk_lds[widx][0];
    unsigned short* kbuf = qk_lds[widx][1];
    float dacc[4] = {0.f, 0.f, 0.f, 0.f};
    char* evbase = ws + WS_EV;
    const f32x4 z = {0.f, 0.f, 0.f, 0.f};

    const int gw = blockIdx.x * 4 + widx;
    for (int i = 0; i < 8; ++i) {
        const int b = gw * 8 + i;
        // A-fragments of X1, X2: lane holds X[c=col][l = quad*8 .. +7]
        const float4* x1p = (const float4*)(e1 + (size_t)b * 512 + col * 32 + quad * 8);
        const float4* x2p = (const float4*)(e2 + (size_t)b * 512 + col * 32 + quad * 8);
        float4 a0 = x1p[0], a1 = x1p[1];
        float4 b0 = x2p[0], b1 = x2p[1];
        s16x8 fx1 = cvt8(a0, a1);
        s16x8 fx2 = cvt8(b0, b1);

        // ---- Q: linears, product, LDS stage (transpose to A-frag layout) ----
        {
            f32x4 q1v[2], q2v[2];
#pragma unroll
            for (int h = 0; h < 2; ++h) {
                q1v[h] = MFMA(fx1, wq[h], cbq[h]);
                q2v[h] = MFMA(fx2, wq[h], cbq[h]);
            }
            // C/D layout: value (h,r) = M[row=quad*4+r][e=col+16h]; LDS rows
            // store permuted e' = e_lo*2 + h (perm shared by Q and K)
#pragma unroll
            for (int r = 0; r < 4; ++r) {
                int w = (quad * 4 + r) * 20 + col;   // uint index, row stride 20 words
                ((unsigned*)qbuf)[w] = pack2(q1v[0][r] * q2v[0][r],
                                             q1v[1][r] * q2v[1][r]);
            }
        }
        // ---- K: same ----
        {
            f32x4 k1v[2], k2v[2];
#pragma unroll
            for (int h = 0; h < 2; ++h) {
                k1v[h] = MFMA(fx1, wk[h], cbk[h]);
                k2v[h] = MFMA(fx2, wk[h], cbk[h]);
            }
#pragma unroll
            for (int r = 0; r < 4; ++r) {
                int w = (quad * 4 + r) * 20 + col;
                ((unsigned*)kbuf)[w] = pack2(k1v[0][r] * k2v[0][r],
                                             k1v[1][r] * k2v[1][r]);
            }
        }
        // ---- V: independent of the LDS round trip — fills its latency shadow
        char* bbase = evbase + (size_t)b * 1536;
        {
            f32x4 v1v[2], v2v[2];
#pragma unroll
            for (int h = 0; h < 2; ++h) {
                v1v[h] = MFMA(fx1, wv[h], cbv[h]);
                v2v[h] = MFMA(fx2, wv[h], cbv[h]);
            }
            // V stored blocked for k2 B-frags: block(h, e_lo=col, c-half quad>>1)
#pragma unroll
            for (int h = 0; h < 2; ++h) {
                uint2 vst;
                vst.x = pack2(v1v[h][0] * v2v[h][0], v1v[h][1] * v2v[h][1]);
                vst.y = pack2(v1v[h][2] * v2v[h][2], v1v[h][3] * v2v[h][3]);
                *(uint2*)(bbase + 512 + ((h * 16 + col) * 2 + (quad >> 1)) * 16 + (quad & 1) * 8) = vst;
            }
        }

        // ---- read back RAW Q as A-frag, K as B-frag; S-MFMA issues at once
        s16x8 aq  = *(const s16x8*)(qbuf + col * 40 + quad * 8);
        s16x8 bk8 = *(const s16x8*)(kbuf + col * 40 + quad * 8);
        f32x4 S = MFMA(aq, bk8, z);   // S_raw[c=quad*4+r][d=col]

        // ---- norms in parallel with the S-MFMA (deferred normalization)
        float ssq = 0.f, ssk = 0.f;
#pragma unroll
        for (int j = 0; j < 8; ++j) {
            float qf = bf2f((unsigned short)aq[j]);  ssq += qf * qf;
            float kf = bf2f((unsigned short)bk8[j]); ssk += kf * kf;
        }
        ssq += __shfl_xor(ssq, 16); ssq += __shfl_xor(ssq, 32);
        ssk += __shfl_xor(ssk, 16); ssk += __shfl_xor(ssk, 32);
        float invq = 1.f / fmaxf(sqrtf(ssq), 1e-12f);   // at lane: row c = col
        float invk = 1.f / fmaxf(sqrtf(ssk), 1e-12f);   // at lane: row d = col
        // transpose invq to row indexing (S rows are quad*4+r)
        float iq0 = __shfl(invq, quad * 4 + 0);
        float iq1 = __shfl(invq, quad * 4 + 1);
        float iq2 = __shfl(invq, quad * 4 + 2);
        float iq3 = __shfl(invq, quad * 4 + 3);

        float ex0 = __expf(S[0] * (iq0 * invk));
        float ex1 = __expf(S[1] * (iq1 * invk));
        float ex2 = __expf(S[2] * (iq2 * invk));
        float ex3 = __expf(S[3] * (iq3 * invk));
        dacc[0] += ex0; dacc[1] += ex1; dacc[2] += ex2; dacc[3] += ex3;
        // E stored [d][c] bf16: lane covers c = quad*4 .. +3 at row d=col
        uint2 est; est.x = pack2(ex0, ex1); est.y = pack2(ex2, ex3);
        *(uint2*)(bbase + col * 32 + quad * 8) = est;
    }
    // Denominator: regs -> block LDS (conflict-free) -> 256 global atomics/block.
    // Blocks drain staggered over k1's span so same-address chains don't pile up.
#pragma unroll
    for (int r = 0; r < 4; ++r)
        atomicAdd(&Dblk[col * 16 + quad * 4 + r], dacc[r]);
    __syncthreads();
    atomicAdd(((float*)ws) + tid, Dblk[tid]);
}

// ---------------------------------------------------------------------------
// k2: cooperative 4-wave block over ONE 16-batch group (R3 structure, best
// measured).  Phase1 (prefetched E/V loads): each wave computes 4 of the 16
// per-batch out[d][e] rows into a shared 16KB H (bf16, XOR-swizzled chunks).
// Phase2 (prefetched weights): each wave takes 4 of the 16 k-tiles of MLP1
// (MFMA), partial accs reduced through LDS (aliased over H).  Phase3: all
// four waves.  dinv = 1/D computed locally (D finalized by k1's atomics).
// ---------------------------------------------------------------------------
__global__ __launch_bounds__(256) void k2_apply(
    const char* __restrict__ ws, const float* __restrict__ p1b,
    const float* __restrict__ p2W, const float* __restrict__ p2b,
    float* __restrict__ out) {

    const int tid = threadIdx.x;
    const int lane = tid & 63;
    const int widx = tid >> 6;
    const int col = lane & 15;
    const int quad = lane >> 4;
    const int qm = quad & 1;        // mirrored address for upper quads

    __shared__ __align__(16) unsigned short Hs[16 * 512];   // 16 KiB
    float* P = (float*)Hs;          // aliased partial-sum buffer (12 KiB <= 16 KiB)

    // Hoisted tail constants — issued first, latency hidden under phases 1-2
    float p1bias[3], p2w[3][3];
#pragma unroll
    for (int nt = 0; nt < 3; ++nt) {
        p1bias[nt] = p1b[col + 16 * nt];
#pragma unroll
        for (int t2 = 0; t2 < 3; ++t2) p2w[nt][t2] = p2W[t2 * 48 + col + 16 * nt];
    }
    const float pb0 = p2b[0], pb1 = p2b[1], pb2 = p2b[2];

    // 1/denominator from D (k1 atomic-finalized), vector-loaded
    const float* Dws = (const float*)ws;
    const float4 dva = *(const float4*)(Dws + col * 16 + qm * 8);
    const float4 dvb = *(const float4*)(Dws + col * 16 + qm * 8 + 4);
    float dinv[8] = {1.f / dva.x, 1.f / dva.y, 1.f / dva.z, 1.f / dva.w,
                     1.f / dvb.x, 1.f / dvb.y, 1.f / dvb.z, 1.f / dvb.w};

    const char* evbase = ws + WS_EV;
    const unsigned short* p1wp = (const unsigned short*)(ws + WS_P1W);
    const int g = blockIdx.x;
    const f32x4 z = {0.f, 0.f, 0.f, 0.f};
    const s16x8 zz = {0, 0, 0, 0, 0, 0, 0, 0};

    // Phase 1: out[d][e] for batches i = widx*4 .. +3 -> H rows (bf16, swizzled)
    {
        const char* bb0 = evbase + (size_t)(g * 16 + widx * 4) * 1536;
        const int eoff  = col * 32 + qm * 16;
        const int voff0 = 512 + (col * 2 + qm) * 16;
        const int voff1 = 512 + ((16 + col) * 2 + qm) * 16;
        s16x8 ne  = *(const s16x8*)(bb0 + eoff);
        s16x8 nv0 = *(const s16x8*)(bb0 + voff0);
        s16x8 nv1 = *(const s16x8*)(bb0 + voff1);
#pragma unroll
        for (int ii = 0; ii < 4; ++ii) {
            s16x8 eraw = ne, bf0 = nv0, bf1 = nv1;
            if (ii < 3) {
                const char* nb = bb0 + (size_t)(ii + 1) * 1536;
                ne  = *(const s16x8*)(nb + eoff);
                nv0 = *(const s16x8*)(nb + voff0);
                nv1 = *(const s16x8*)(nb + voff1);
            }
            float ef[8];
#pragma unroll
            for (int j = 0; j < 8; ++j)
                ef[j] = bf2f((unsigned short)eraw[j]) * dinv[j];
            uint4 ua;
            ua.x = pack2(ef[0], ef[1]); ua.y = pack2(ef[2], ef[3]);
            ua.z = pack2(ef[4], ef[5]); ua.w = pack2(ef[6], ef[7]);
            s16x8 afrag = __builtin_bit_cast(s16x8, ua);
            if (quad >= 2) { afrag = zz; bf0 = zz; bf1 = zz; }  // K-padding (c>=16 -> 0)
            f32x4 o0 = MFMA(afrag, bf0, z);   // out[d=quad*4+r][e=col]
            f32x4 o1 = MFMA(afrag, bf1, z);   // out[d=quad*4+r][e=col+16]
            uint4 uh;
            uh.x = pack2(o0[0], o0[1]); uh.y = pack2(o0[2], o0[3]);
            uh.z = pack2(o1[0], o1[1]); uh.w = pack2(o1[2], o1[3]);
            const int i = widx * 4 + ii;
            int chunk = (col * 4 + quad) ^ (i & 7);   // 16B-chunk XOR swizzle
            *(uint4*)(Hs + i * 512 + chunk * 8) = uh;
        }
    }
    __syncthreads();

    // Phase 2: MLP1 — H[16 x 512] @ p1Wp^T, wave widx handles kt = widx*4..+3
    f32x4 acc[3] = {z, z, z};
    {
        const int kt0 = widx * 4;
        s16x8 nw0 = *(const s16x8*)(p1wp + ((0 * 16 + kt0) * 64 + lane) * 8);
        s16x8 nw1 = *(const s16x8*)(p1wp + ((1 * 16 + kt0) * 64 + lane) * 8);
        s16x8 nw2 = *(const s16x8*)(p1wp + ((2 * 16 + kt0) * 64 + lane) * 8);
#pragma unroll
        for (int t2 = 0; t2 < 4; ++t2) {
            const int kt = widx * 4 + t2;
            s16x8 w0 = nw0, w1 = nw1, w2 = nw2;
            if (t2 < 3) {
                nw0 = *(const s16x8*)(p1wp + ((0 * 16 + kt + 1) * 64 + lane) * 8);
                nw1 = *(const s16x8*)(p1wp + ((1 * 16 + kt + 1) * 64 + lane) * 8);
                nw2 = *(const s16x8*)(p1wp + ((2 * 16 + kt + 1) * 64 + lane) * 8);
            }
            int chunk = (kt * 4 + quad) ^ (col & 7);
            s16x8 a = *(const s16x8*)(Hs + col * 512 + chunk * 8);
            acc[0] = MFMA(a, w0, acc[0]);
            acc[1] = MFMA(a, w1, acc[1]);
            acc[2] = MFMA(a, w2, acc[2]);
        }
    }
    __syncthreads();   // H reads done before P overwrites it

    // partials -> LDS: P[widx][lane][nt*4+r], lane stride 12 floats (48B)
#pragma unroll
    for (int nt = 0; nt < 3; ++nt)
        *(f32x4*)(P + (widx * 64 + lane) * 12 + nt * 4) = acc[nt];
    __syncthreads();

    // Phase 3: all 4 waves — wave widx handles r = widx (batches quad*4+widx)
    {
        float s3[3] = {0.f, 0.f, 0.f};
#pragma unroll
        for (int w = 0; w < 4; ++w)
#pragma unroll
            for (int nt = 0; nt < 3; ++nt)
                s3[nt] += P[(w * 64 + lane) * 12 + nt * 4 + widx];
        float pp[3] = {0.f, 0.f, 0.f};
#pragma unroll
        for (int nt = 0; nt < 3; ++nt) {
            float hv = fmaxf(s3[nt] + p1bias[nt], 0.f);
            pp[0] += hv * p2w[nt][0];
            pp[1] += hv * p2w[nt][1];
            pp[2] += hv * p2w[nt][2];
        }
#pragma unroll
        for (int m = 1; m <= 8; m <<= 1) {
            pp[0] += __shfl_xor(pp[0], m);
            pp[1] += __shfl_xor(pp[1], m);
            pp[2] += __shfl_xor(pp[2], m);
        }
        float h0 = pp[0] + pb0, h1 = pp[1] + pb1, h2 = pp[2] + pb2;
        float inv = 1.f / fmaxf(sqrtf(h0 * h0 + h1 * h1 + h2 * h2), 1e-12f);
        if (col < 3) {
            float v = (col == 0) ? h0 : ((col == 1) ? h1 : h2);
            out[(size_t)(g * 16 + quad * 4 + widx) * 3 + col] = v * inv;
        }
    }
}

// ---------------------------------------------------------------------------
extern "C" void kernel_launch(void* const* d_in, const int* in_sizes, int n_in,
                              void* d_out, int out_size, void* d_ws, size_t ws_size,
                              hipStream_t stream) {
    const float* e1  = (const float*)d_in[0];
    const float* e2  = (const float*)d_in[1];
    const float* qW  = (const float*)d_in[2];
    const float* qb  = (const float*)d_in[3];
    const float* kW  = (const float*)d_in[4];
    const float* kb  = (const float*)d_in[5];
    const float* vW  = (const float*)d_in[6];
    const float* vb  = (const float*)d_in[7];
    const float* p1W = (const float*)d_in[8];
    const float* p1b = (const float*)d_in[9];
    const float* p2W = (const float*)d_in[10];
    const float* p2b = (const float*)d_in[11];
    float* out = (float*)d_out;
    char* ws = (char*)d_ws;

    (void)hipMemsetAsync(ws, 0, 1024, stream);   // zero D accumulators (stream-ordered)
    k1_stats<<<2048, 256, 0, stream>>>(e1, e2, qW, qb, kW, kb, vW, vb, p1W, ws);
    k2_apply<<<4096, 256, 0, stream>>>(ws, p1b, p2W, p2b, out);
}

// Round 10
// 343.091 us; speedup vs baseline: 1.2196x; 1.0081x over previous
//
#include <hip/hip_runtime.h>

// Problem constants
#define B_TOT 65536
#define WS_P1W 4096                 // permuted bf16 p1W: 48*512*2 = 49152 B
#define WS_EV  (1u << 20)           // per-batch blocks: 512B E + 1024B V = 1536 B * 65536

typedef float f32x4 __attribute__((ext_vector_type(4)));
typedef short s16x8 __attribute__((ext_vector_type(8)));

__device__ __forceinline__ float bf2f(unsigned short h) {
    unsigned u = ((unsigned)h) << 16;
    return __builtin_bit_cast(float, u);
}
// cheap bf16 pair pack: round-half-up (add 0x8000) + v_perm_b32 high-half merge.
__device__ __forceinline__ unsigned pack2(float a, float b) {
    unsigned ua = __builtin_bit_cast(unsigned, a) + 0x8000u;
    unsigned ub = __builtin_bit_cast(unsigned, b) + 0x8000u;
    return __builtin_amdgcn_perm(ub, ua, 0x07060302u);  // lo16=a, hi16=b
}
__device__ __forceinline__ unsigned short f2bf(float f) {
    return (unsigned short)((__builtin_bit_cast(unsigned, f) + 0x8000u) >> 16);
}
__device__ __forceinline__ s16x8 cvt8(float4 a, float4 b) {
    uint4 u;
    u.x = pack2(a.x, a.y); u.y = pack2(a.z, a.w);
    u.z = pack2(b.x, b.y); u.w = pack2(b.z, b.w);
    return __builtin_bit_cast(s16x8, u);
}
// sum of squares of the two bf16 halves of a packed dword (bit-exact with
// squaring the bf16-rounded values the S-MFMA consumes)
__device__ __forceinline__ float ss2(unsigned w, float acc) {
    float lo = __builtin_bit_cast(float, w << 16);
    float hi = __builtin_bit_cast(float, w & 0xffff0000u);
    return acc + lo * lo + hi * hi;
}
#define MFMA(a, b, c) __builtin_amdgcn_mfma_f32_16x16x32_bf16((a), (b), (c), 0, 0, 0)

// ---------------------------------------------------------------------------
// k1: ZERO-LDS Q/K path via SWAPPED MFMA OPERANDS.
// Key identity: mfma(A=W, B=X) emits the linear output TRANSPOSED (C/D lane
// col = batch-row c, regs = e-rows quad*4+r+16h) — which IS the A/B-fragment
// orientation the S-MFMA needs.  Q,K products are packed bf16 in a fixed e'
// permutation (e'(quad*8+j) = quad*4+(j&3)+16*(j>>2), identical for Q and K,
// so Q·K is invariant) and fed to S = mfma(aq, bk) STRAIGHT FROM REGISTERS.
// The entire LDS transpose round-trip (8 ds_writes + 2 ds_read_b128 + ~200-
// 400 cy latency per iteration, R0-R9's structural serial element) is GONE.
// V keeps the original operand order (its C/D layout feeds k2's blocked
// store directly).  Norms: unpack the packed bf16 (register ops) -> same
// numerics as the LDS-round-trip baseline; same shfl reduction pattern.
// Q/K biases: per-row float4 (qb[16h+quad*4+r]) in the accumulator.
// Kept from R9: folded p1W permute, atomic D finalize, 1KB memset, plain
// E/V stores (R8: nt-stores cost +13us and broke k2's L3 reuse).
// ---------------------------------------------------------------------------
__global__ __launch_bounds__(256) void k1_stats(
    const float* __restrict__ e1, const float* __restrict__ e2,
    const float* __restrict__ qW, const float* __restrict__ qb,
    const float* __restrict__ kW, const float* __restrict__ kb,
    const float* __restrict__ vW, const float* __restrict__ vb,
    const float* __restrict__ p1W, char* __restrict__ ws) {

    const int tid = threadIdx.x;
    const int lane = tid & 63;
    const int widx = tid >> 6;
    const int col = lane & 15;      // n-index in MFMA layouts
    const int quad = lane >> 4;

    __shared__ float Dblk[256];
    Dblk[tid] = 0.f;

    // Folded permute: blocks 0..95 each emit 256 elems of bf16 p1W in k2's
    // i' order.  Independent of batch work; read by k2 only.
    if (blockIdx.x < 96) {
        int idx = blockIdx.x * 256 + tid;        // 96*256 = 24576 = 48*512
        int jj   = idx & 7;
        int l2   = (idx >> 3) & 63;
        int ktnt = idx >> 9;
        int kt = ktnt & 15, nt = ktnt >> 4;
        int n_lo = l2 & 15, q8 = l2 >> 4;
        int j2  = nt * 16 + n_lo;                // output neuron [0,48)
        int ip  = kt * 32 + q8 * 8 + jj;         // i' in [0,512)
        int e_lo = ip >> 5, qq = (ip >> 3) & 3, hh = (ip >> 2) & 1, r = ip & 3;
        int orig = (qq * 4 + r) * 32 + (e_lo + 16 * hh);
        ((unsigned short*)(ws + WS_P1W))[idx] = f2bf(p1W[j2 * 512 + orig]);
    }
    __syncthreads();

    // Weight fragments: lane holds W[col+16h][quad*8..+7] — serves as the
    // A-operand of the swapped linears (A[m=e][k=l]) for Q,K and as the
    // B-operand for V's original-order linear.
    s16x8 wq[2], wk[2], wv[2];
    f32x4 cbq[2], cbk[2];           // swapped-order bias: per-ROW (e) float4
    f32x4 cbv[2];                   // V bias: splat per e=col+16h (original order)
#pragma unroll
    for (int h = 0; h < 2; ++h) {
        int row = col + 16 * h;
        const float4* pq = (const float4*)(qW + row * 32 + quad * 8);
        const float4* pk = (const float4*)(kW + row * 32 + quad * 8);
        const float4* pv = (const float4*)(vW + row * 32 + quad * 8);
        wq[h] = cvt8(pq[0], pq[1]);
        wk[h] = cvt8(pk[0], pk[1]);
        wv[h] = cvt8(pv[0], pv[1]);
        float4 qb4 = *(const float4*)(qb + 16 * h + quad * 4);
        float4 kb4 = *(const float4*)(kb + 16 * h + quad * 4);
        cbq[h] = (f32x4){qb4.x, qb4.y, qb4.z, qb4.w};
        cbk[h] = (f32x4){kb4.x, kb4.y, kb4.z, kb4.w};
        float vv_ = vb[row];
        cbv[h] = (f32x4){vv_, vv_, vv_, vv_};
    }

    float dacc[4] = {0.f, 0.f, 0.f, 0.f};
    char* evbase = ws + WS_EV;
    const f32x4 z = {0.f, 0.f, 0.f, 0.f};

    const int gw = blockIdx.x * 4 + widx;
    for (int i = 0; i < 8; ++i) {
        const int b = gw * 8 + i;
        // X fragments: lane holds X[c=col][l = quad*8 .. +7] — serves as the
        // B-operand of swapped linears (B[k=l][n=c]) and A-operand for V.
        const float4* x1p = (const float4*)(e1 + (size_t)b * 512 + col * 32 + quad * 8);
        const float4* x2p = (const float4*)(e2 + (size_t)b * 512 + col * 32 + quad * 8);
        float4 a0 = x1p[0], a1 = x1p[1];
        float4 b0 = x2p[0], b1 = x2p[1];
        s16x8 fx1 = cvt8(a0, a1);
        s16x8 fx2 = cvt8(b0, b1);

        // ---- Q swapped linears: C[m=e][n=c]; lane holds Qt[e=quad*4+r+16h][c=col]
        uint4 uq;
        {
            f32x4 q1a = MFMA(wq[0], fx1, cbq[0]);
            f32x4 q2a = MFMA(wq[0], fx2, cbq[0]);
            f32x4 q1b = MFMA(wq[1], fx1, cbq[1]);
            f32x4 q2b = MFMA(wq[1], fx2, cbq[1]);
            uq.x = pack2(q1a[0] * q2a[0], q1a[1] * q2a[1]);
            uq.y = pack2(q1a[2] * q2a[2], q1a[3] * q2a[3]);
            uq.z = pack2(q1b[0] * q2b[0], q1b[1] * q2b[1]);
            uq.w = pack2(q1b[2] * q2b[2], q1b[3] * q2b[3]);
        }
        // ---- K swapped linears ----
        uint4 uk;
        {
            f32x4 k1a = MFMA(wk[0], fx1, cbk[0]);
            f32x4 k2a = MFMA(wk[0], fx2, cbk[0]);
            f32x4 k1b = MFMA(wk[1], fx1, cbk[1]);
            f32x4 k2b = MFMA(wk[1], fx2, cbk[1]);
            uk.x = pack2(k1a[0] * k2a[0], k1a[1] * k2a[1]);
            uk.y = pack2(k1a[2] * k2a[2], k1a[3] * k2a[3]);
            uk.z = pack2(k1b[0] * k2b[0], k1b[1] * k2b[1]);
            uk.w = pack2(k1b[2] * k2b[2], k1b[3] * k2b[3]);
        }
        s16x8 aq  = __builtin_bit_cast(s16x8, uq);   // A[m=c][k=e'] fragment
        s16x8 bk8 = __builtin_bit_cast(s16x8, uk);   // B[k=e'][n=d] fragment
        f32x4 S = MFMA(aq, bk8, z);   // S_raw[c=quad*4+r][d=col] — same as R9

        // ---- V: original operand order (C/D lane = e-column, feeds k2 store)
        char* bbase = evbase + (size_t)b * 1536;
        {
            f32x4 v1v[2], v2v[2];
#pragma unroll
            for (int h = 0; h < 2; ++h) {
                v1v[h] = MFMA(fx1, wv[h], cbv[h]);
                v2v[h] = MFMA(fx2, wv[h], cbv[h]);
            }
            // V stored blocked for k2 B-frags: block(h, e_lo=col, c-half quad>>1)
#pragma unroll
            for (int h = 0; h < 2; ++h) {
                uint2 vst;
                vst.x = pack2(v1v[h][0] * v2v[h][0], v1v[h][1] * v2v[h][1]);
                vst.y = pack2(v1v[h][2] * v2v[h][2], v1v[h][3] * v2v[h][3]);
                *(uint2*)(bbase + 512 + ((h * 16 + col) * 2 + (quad >> 1)) * 16 + (quad & 1) * 8) = vst;
            }
        }

        // ---- norms from the packed bf16 (numerics == old LDS readback path)
        float ssq = 0.f, ssk = 0.f;
        ssq = ss2(uq.x, ssq); ssq = ss2(uq.y, ssq);
        ssq = ss2(uq.z, ssq); ssq = ss2(uq.w, ssq);
        ssk = ss2(uk.x, ssk); ssk = ss2(uk.y, ssk);
        ssk = ss2(uk.z, ssk); ssk = ss2(uk.w, ssk);
        ssq += __shfl_xor(ssq, 16); ssq += __shfl_xor(ssq, 32);
        ssk += __shfl_xor(ssk, 16); ssk += __shfl_xor(ssk, 32);
        float invq = 1.f / fmaxf(sqrtf(ssq), 1e-12f);   // valid at lanes col=c
        float invk = 1.f / fmaxf(sqrtf(ssk), 1e-12f);   // lane-local: col=d
        float iq0 = __shfl(invq, quad * 4 + 0);
        float iq1 = __shfl(invq, quad * 4 + 1);
        float iq2 = __shfl(invq, quad * 4 + 2);
        float iq3 = __shfl(invq, quad * 4 + 3);

        float ex0 = __expf(S[0] * (iq0 * invk));
        float ex1 = __expf(S[1] * (iq1 * invk));
        float ex2 = __expf(S[2] * (iq2 * invk));
        float ex3 = __expf(S[3] * (iq3 * invk));
        dacc[0] += ex0; dacc[1] += ex1; dacc[2] += ex2; dacc[3] += ex3;
        // E stored [d][c] bf16: lane covers c = quad*4 .. +3 at row d=col
        uint2 est; est.x = pack2(ex0, ex1); est.y = pack2(ex2, ex3);
        *(uint2*)(bbase + col * 32 + quad * 8) = est;
    }
    // Denominator: regs -> block LDS (conflict-free) -> 256 global atomics/block
#pragma unroll
    for (int r = 0; r < 4; ++r)
        atomicAdd(&Dblk[col * 16 + quad * 4 + r], dacc[r]);
    __syncthreads();
    atomicAdd(((float*)ws) + tid, Dblk[tid]);
}

// ---------------------------------------------------------------------------
// k2: cooperative 4-wave block over ONE 16-batch group (R3 structure, best
// measured).  Phase1 (prefetched E/V loads): each wave computes 4 of the 16
// per-batch out[d][e] rows into a shared 16KB H (bf16, XOR-swizzled chunks).
// Phase2 (prefetched weights): each wave takes 4 of the 16 k-tiles of MLP1
// (MFMA), partial accs reduced through LDS (aliased over H).  Phase3: all
// four waves.  dinv = 1/D computed locally (D finalized by k1's atomics).
// ---------------------------------------------------------------------------
__global__ __launch_bounds__(256) void k2_apply(
    const char* __restrict__ ws, const float* __restrict__ p1b,
    const float* __restrict__ p2W, const float* __restrict__ p2b,
    float* __restrict__ out) {

    const int tid = threadIdx.x;
    const int lane = tid & 63;
    const int widx = tid >> 6;
    const int col = lane & 15;
    const int quad = lane >> 4;
    const int qm = quad & 1;        // mirrored address for upper quads

    __shared__ __align__(16) unsigned short Hs[16 * 512];   // 16 KiB
    float* P = (float*)Hs;          // aliased partial-sum buffer (12 KiB <= 16 KiB)

    // Hoisted tail constants — issued first, latency hidden under phases 1-2
    float p1bias[3], p2w[3][3];
#pragma unroll
    for (int nt = 0; nt < 3; ++nt) {
        p1bias[nt] = p1b[col + 16 * nt];
#pragma unroll
        for (int t2 = 0; t2 < 3; ++t2) p2w[nt][t2] = p2W[t2 * 48 + col + 16 * nt];
    }
    const float pb0 = p2b[0], pb1 = p2b[1], pb2 = p2b[2];

    // 1/denominator from D (k1 atomic-finalized), vector-loaded
    const float* Dws = (const float*)ws;
    const float4 dva = *(const float4*)(Dws + col * 16 + qm * 8);
    const float4 dvb = *(const float4*)(Dws + col * 16 + qm * 8 + 4);
    float dinv[8] = {1.f / dva.x, 1.f / dva.y, 1.f / dva.z, 1.f / dva.w,
                     1.f / dvb.x, 1.f / dvb.y, 1.f / dvb.z, 1.f / dvb.w};

    const char* evbase = ws + WS_EV;
    const unsigned short* p1wp = (const unsigned short*)(ws + WS_P1W);
    const int g = blockIdx.x;
    const f32x4 z = {0.f, 0.f, 0.f, 0.f};
    const s16x8 zz = {0, 0, 0, 0, 0, 0, 0, 0};

    // Phase 1: out[d][e] for batches i = widx*4 .. +3 -> H rows (bf16, swizzled)
    {
        const char* bb0 = evbase + (size_t)(g * 16 + widx * 4) * 1536;
        const int eoff  = col * 32 + qm * 16;
        const int voff0 = 512 + (col * 2 + qm) * 16;
        const int voff1 = 512 + ((16 + col) * 2 + qm) * 16;
        s16x8 ne  = *(const s16x8*)(bb0 + eoff);
        s16x8 nv0 = *(const s16x8*)(bb0 + voff0);
        s16x8 nv1 = *(const s16x8*)(bb0 + voff1);
#pragma unroll
        for (int ii = 0; ii < 4; ++ii) {
            s16x8 eraw = ne, bf0 = nv0, bf1 = nv1;
            if (ii < 3) {
                const char* nb = bb0 + (size_t)(ii + 1) * 1536;
                ne  = *(const s16x8*)(nb + eoff);
                nv0 = *(const s16x8*)(nb + voff0);
                nv1 = *(const s16x8*)(nb + voff1);
            }
            float ef[8];
#pragma unroll
            for (int j = 0; j < 8; ++j)
                ef[j] = bf2f((unsigned short)eraw[j]) * dinv[j];
            uint4 ua;
            ua.x = pack2(ef[0], ef[1]); ua.y = pack2(ef[2], ef[3]);
            ua.z = pack2(ef[4], ef[5]); ua.w = pack2(ef[6], ef[7]);
            s16x8 afrag = __builtin_bit_cast(s16x8, ua);
            if (quad >= 2) { afrag = zz; bf0 = zz; bf1 = zz; }  // K-padding (c>=16 -> 0)
            f32x4 o0 = MFMA(afrag, bf0, z);   // out[d=quad*4+r][e=col]
            f32x4 o1 = MFMA(afrag, bf1, z);   // out[d=quad*4+r][e=col+16]
            uint4 uh;
            uh.x = pack2(o0[0], o0[1]); uh.y = pack2(o0[2], o0[3]);
            uh.z = pack2(o1[0], o1[1]); uh.w = pack2(o1[2], o1[3]);
            const int i = widx * 4 + ii;
            int chunk = (col * 4 + quad) ^ (i & 7);   // 16B-chunk XOR swizzle
            *(uint4*)(Hs + i * 512 + chunk * 8) = uh;
        }
    }
    __syncthreads();

    // Phase 2: MLP1 — H[16 x 512] @ p1Wp^T, wave widx handles kt = widx*4..+3
    f32x4 acc[3] = {z, z, z};
    {
        const int kt0 = widx * 4;
        s16x8 nw0 = *(const s16x8*)(p1wp + ((0 * 16 + kt0) * 64 + lane) * 8);
        s16x8 nw1 = *(const s16x8*)(p1wp + ((1 * 16 + kt0) * 64 + lane) * 8);
        s16x8 nw2 = *(const s16x8*)(p1wp + ((2 * 16 + kt0) * 64 + lane) * 8);
#pragma unroll
        for (int t2 = 0; t2 < 4; ++t2) {
            const int kt = widx * 4 + t2;
            s16x8 w0 = nw0, w1 = nw1, w2 = nw2;
            if (t2 < 3) {
                nw0 = *(const s16x8*)(p1wp + ((0 * 16 + kt + 1) * 64 + lane) * 8);
                nw1 = *(const s16x8*)(p1wp + ((1 * 16 + kt + 1) * 64 + lane) * 8);
                nw2 = *(const s16x8*)(p1wp + ((2 * 16 + kt + 1) * 64 + lane) * 8);
            }
            int chunk = (kt * 4 + quad) ^ (col & 7);
            s16x8 a = *(const s16x8*)(Hs + col * 512 + chunk * 8);
            acc[0] = MFMA(a, w0, acc[0]);
            acc[1] = MFMA(a, w1, acc[1]);
            acc[2] = MFMA(a, w2, acc[2]);
        }
    }
    __syncthreads();   // H reads done before P overwrites it

    // partials -> LDS: P[widx][lane][nt*4+r], lane stride 12 floats (48B)
#pragma unroll
    for (int nt = 0; nt < 3; ++nt)
        *(f32x4*)(P + (widx * 64 + lane) * 12 + nt * 4) = acc[nt];
    __syncthreads();

    // Phase 3: all 4 waves — wave widx handles r = widx (batches quad*4+widx)
    {
        float s3[3] = {0.f, 0.f, 0.f};
#pragma unroll
        for (int w = 0; w < 4; ++w)
#pragma unroll
            for (int nt = 0; nt < 3; ++nt)
                s3[nt] += P[(w * 64 + lane) * 12 + nt * 4 + widx];
        float pp[3] = {0.f, 0.f, 0.f};
#pragma unroll
        for (int nt = 0; nt < 3; ++nt) {
            float hv = fmaxf(s3[nt] + p1bias[nt], 0.f);
            pp[0] += hv * p2w[nt][0];
            pp[1] += hv * p2w[nt][1];
            pp[2] += hv * p2w[nt][2];
        }
#pragma unroll
        for (int m = 1; m <= 8; m <<= 1) {
            pp[0] += __shfl_xor(pp[0], m);
            pp[1] += __shfl_xor(pp[1], m);
            pp[2] += __shfl_xor(pp[2], m);
        }
        float h0 = pp[0] + pb0, h1 = pp[1] + pb1, h2 = pp[2] + pb2;
        float inv = 1.f / fmaxf(sqrtf(h0 * h0 + h1 * h1 + h2 * h2), 1e-12f);
        if (col < 3) {
            float v = (col == 0) ? h0 : ((col == 1) ? h1 : h2);
            out[(size_t)(g * 16 + quad * 4 + widx) * 3 + col] = v * inv;
        }
    }
}

// ---------------------------------------------------------------------------
extern "C" void kernel_launch(void* const* d_in, const int* in_sizes, int n_in,
                              void* d_out, int out_size, void* d_ws, size_t ws_size,
                              hipStream_t stream) {
    const float* e1  = (const float*)d_in[0];
    const float* e2  = (const float*)d_in[1];
    const float* qW  = (const float*)d_in[2];
    const float* qb  = (const float*)d_in[3];
    const float* kW  = (const float*)d_in[4];
    const float* kb  = (const float*)d_in[5];
    const float* vW  = (const float*)d_in[6];
    const float* vb  = (const float*)d_in[7];
    const float* p1W = (const float*)d_in[8];
    const float* p1b = (const float*)d_in[9];
    const float* p2W = (const float*)d_in[10];
    const float* p2b = (const float*)d_in[11];
    float* out = (float*)d_out;
    char* ws = (char*)d_ws;

    (void)hipMemsetAsync(ws, 0, 1024, stream);   // zero D accumulators (stream-ordered)
    k1_stats<<<2048, 256, 0, stream>>>(e1, e2, qW, qb, kW, kb, vW, vb, p1W, ws);
    k2_apply<<<4096, 256, 0, stream>>>(ws, p1b, p2W, p2b, out);
}